// Round 2
// baseline (726.227 us; speedup 1.0000x reference)
//
#include <hip/hip_runtime.h>

namespace {

constexpr int kB  = 16;
constexpr int kNC = 31;
constexpr int kNX = 256;   // rows (H)
constexpr int kNY = 256;   // cols (W)
constexpr int kNO = 3;
constexpr int kKS = 17;
constexpr int NOC = kNO * kNC;   // 93

constexpr int TX = 64;           // output cols per block
constexpr int TY = 32;           // output rows per block
constexpr int HTY = TY + 8;      // 40 staged rows (halo +-4)
constexpr int XP  = 84;          // tile pitch: mult of 4 (b128-aligned rows); 84%32=20 -> even bank spread
constexpr int WROW = 16;         // padded weight row (floats) for uniform s_load

// ---------------------------------------------------------------------------
// prep: ReLU the sparse kernel values into d_ws (padded rows of 16) and decode
// the per-(order,channel) horizontal shift so = cx-4 in [0,8] from locations.
// ---------------------------------------------------------------------------
__global__ void prep(const float* __restrict__ vk, const int* __restrict__ loc,
                     float* __restrict__ wrel, int* __restrict__ soTab)
{
    int i = blockIdx.x * 256 + threadIdx.x;
    if (i < NOC * 9 * WROW) {
        int dx  = i & 15;
        int row = i >> 4;              // row = oc*9 + dy
        float v = 0.0f;
        if (dx < 9) {
            float t = vk[row * 9 + dx];
            v = t > 0.0f ? t : 0.0f;
        }
        wrel[i] = v;
    }
    if (i < NOC) {
        // locations[oc*81] = ((oc*17 + 4)*17) + cx - 4  ->  recover cx
        int cx = loc[i * 81] - (i * kKS + 4) * kKS + 4;
        soTab[i] = cx - 4;             // so in [0,8]
    }
}

template<int S>
__device__ __forceinline__ void extract16(float* __restrict__ xr,
                                          const float* __restrict__ xu)
{
    #pragma unroll
    for (int i = 0; i < 16; ++i) xr[i] = xu[i + S];
}

// out[b,o,y,x] = sum_{c,dy,dx} wrel[oc][dy][dx] * xtile[y+dy-4][x + so(oc) + dx - 8]
__global__ __launch_bounds__(256, 4)
void disperse_conv(const float* __restrict__ x,
                   const float* __restrict__ wrel,
                   const int* __restrict__ soTab,
                   float* __restrict__ out)
{
    __shared__ __align__(16) float xtile[HTY * XP];   // 13,440 B

    const int tid = threadIdx.x;
    const int x0 = blockIdx.x * TX;
    const int y0 = blockIdx.y * TY;
    const int b  = blockIdx.z;

    const int tx = tid & 7;            // 8 threads across x
    const int ty = tid >> 3;           // 32 threads down y
    const int xo = tx * 8;             // 8 consecutive output cols per thread

    float acc[kNO][8];
    #pragma unroll
    for (int o = 0; o < kNO; ++o)
        #pragma unroll
        for (int j = 0; j < 8; ++j)
            acc[o][j] = 0.0f;

    for (int c = 0; c < kNC; ++c) {
        __syncthreads();   // protect previous tile before overwrite
        // --- stage x tile: rows y0-4..y0+35, cols x0-8..x0+71, zero-padded ---
        const float* xc = x + (size_t)(b * kNC + c) * kNX * kNY;
        #pragma unroll
        for (int it = 0; it < 4; ++it) {           // 800 float4 over 256 threads
            int i = it * 256 + tid;
            if (i < HTY * 20) {
                int r = i / 20;
                int k = i - r * 20;
                int gy = y0 - 4 + r;
                int gx = x0 - 8 + k * 4;           // mult of 4: aligned global f4
                float4 v = make_float4(0.f, 0.f, 0.f, 0.f);
                if ((unsigned)gy < (unsigned)kNX && (unsigned)gx < (unsigned)kNY)
                    v = *(const float4*)(xc + (size_t)gy * kNY + gx);
                *(float4*)&xtile[r * XP + k * 4] = v;   // b128, aligned
            }
        }
        __syncthreads();

        // wave-uniform shifts for the 3 orders at this channel (s_load)
        const int so0 = soTab[0 * kNC + c];
        const int so1 = soTab[1 * kNC + c];
        const int so2 = soTab[2 * kNC + c];

        #pragma unroll 1
        for (int dy = 0; dy < 9; ++dy) {
            // union span: 24 floats cover all shifts for all 3 orders
            float xu[24];
            const float* srow = &xtile[(ty + dy) * XP + xo];  // 16B aligned
            #pragma unroll
            for (int k2 = 0; k2 < 6; ++k2)
                *(float4*)&xu[k2 * 4] = *(const float4*)&srow[k2 * 4];

            #pragma unroll
            for (int o = 0; o < kNO; ++o) {
                const int oc = o * kNC + c;
                const int so = (o == 0) ? so0 : (o == 1) ? so1 : so2;
                // weights: uniform address -> scalar loads, no LDS, no VGPRs
                const float* wr = &wrel[(oc * 9 + dy) * WROW];
                float w[9];
                #pragma unroll
                for (int d = 0; d < 9; ++d) w[d] = wr[d];

                // wave-uniform switch -> statically indexed register extraction
                float xr[16];
                switch (so) {
                    case 0: extract16<0>(xr, xu); break;
                    case 1: extract16<1>(xr, xu); break;
                    case 2: extract16<2>(xr, xu); break;
                    case 3: extract16<3>(xr, xu); break;
                    case 4: extract16<4>(xr, xu); break;
                    case 5: extract16<5>(xr, xu); break;
                    case 6: extract16<6>(xr, xu); break;
                    case 7: extract16<7>(xr, xu); break;
                    default: extract16<8>(xr, xu); break;
                }

                #pragma unroll
                for (int d = 0; d < 9; ++d)
                    #pragma unroll
                    for (int j = 0; j < 8; ++j)
                        acc[o][j] = fmaf(w[d], xr[j + d], acc[o][j]);
            }
        }
    }

    // --- epilogue: 3 orders x 8 cols per thread, float4 stores ---
    #pragma unroll
    for (int o = 0; o < kNO; ++o) {
        size_t base = (((size_t)b * kNO + o) * kNX + (size_t)(y0 + ty)) * kNY
                      + (size_t)(x0 + xo);
        *(float4*)(out + base)     = make_float4(acc[o][0], acc[o][1], acc[o][2], acc[o][3]);
        *(float4*)(out + base + 4) = make_float4(acc[o][4], acc[o][5], acc[o][6], acc[o][7]);
    }
}

} // namespace

extern "C" void kernel_launch(void* const* d_in, const int* in_sizes, int n_in,
                              void* d_out, int out_size, void* d_ws, size_t ws_size,
                              hipStream_t stream)
{
    const float* x  = (const float*)d_in[0];
    const float* vk = (const float*)d_in[1];
    const int* loc  = (const int*)d_in[2];
    float* outp = (float*)d_out;

    float* wrel = (float*)d_ws;                       // 93*9*16 floats = 53,568 B
    int*   soTab = (int*)(wrel + NOC * 9 * WROW);     // 93 ints

    dim3 pgrid((NOC * 9 * WROW + 255) / 256);
    hipLaunchKernelGGL(prep, pgrid, dim3(256), 0, stream, vk, loc, wrel, soTab);

    dim3 grid(kNY / TX, kNX / TY, kB);   // (4, 8, 16) = 512 blocks
    hipLaunchKernelGGL(disperse_conv, grid, dim3(256), 0, stream,
                       x, wrel, soTab, outp);
}